// Round 5
// baseline (1233.808 us; speedup 1.0000x reference)
//
#include <hip/hip_runtime.h>
#include <math.h>

#define N_NODES 50000
#define N_EDGES 800000
#define FEAT    16
#define HID     64
#define KORD    32
#define NCLS    8

// W[d,k,f,c] flat index = (d*KORD + k)*80*64 + f*64 + c ; only rows f<16 matter (H0==0).
#define WSL     5120   // 80*64, per-(d,k) slice stride in floats
#define SLOT    (N_NODES * FEAT)   // 800000 floats per slab slot

static constexpr size_t Aln(size_t x) { return (x + 255) & ~size_t(255); }

// ---- workspace layout (bytes), total ~66 MB ----
static constexpr size_t OFF_DEG_OUT = 0;
static constexpr size_t OFF_DEG_IN  = OFF_DEG_OUT + Aln(N_NODES * 4);
static constexpr size_t OFF_CUR_DST = OFF_DEG_IN  + Aln(N_NODES * 4);
static constexpr size_t OFF_CUR_SRC = OFF_CUR_DST + Aln(N_NODES * 4);
static constexpr size_t ZERO_BYTES  = OFF_CUR_SRC + Aln(N_NODES * 4);   // zero [0, ZERO_BYTES)
static constexpr size_t OFF_OFF_DST = ZERO_BYTES;
static constexpr size_t OFF_OFF_SRC = OFF_OFF_DST + Aln((N_NODES + 1) * 4);
static constexpr size_t OFF_CSRD    = OFF_OFF_SRC + Aln((N_NODES + 1) * 4);  // int2{idx, w_f32}
static constexpr size_t OFF_CSRS    = OFF_CSRD + Aln(N_EDGES * 8);
static constexpr size_t OFF_HZ      = OFF_CSRS + Aln(N_EDGES * 8);
static constexpr size_t OFF_HH      = OFF_HZ  + Aln(N_NODES * HID * 4);
static constexpr size_t OFF_SLAB    = OFF_HH  + Aln(N_NODES * HID * 4);      // 8 slots f32
static constexpr size_t OFF_WCAT    = OFF_SLAB + Aln((size_t)8 * SLOT * 4);
static constexpr size_t WS_TOTAL    = OFF_WCAT + Aln((size_t)64 * 16 * 128 * 4);

__global__ void count_deg_kernel(const int* __restrict__ ei,
                                 int* __restrict__ deg_out, int* __restrict__ deg_in) {
    int e4 = blockIdx.x * blockDim.x + threadIdx.x;   // 4 edges per thread
    if (e4 * 4 >= N_EDGES) return;
    int4 s = *(const int4*)&ei[e4 * 4];
    int4 d = *(const int4*)&ei[N_EDGES + e4 * 4];
    atomicAdd(&deg_out[s.x], 1); atomicAdd(&deg_out[s.y], 1);
    atomicAdd(&deg_out[s.z], 1); atomicAdd(&deg_out[s.w], 1);
    atomicAdd(&deg_in[d.x], 1);  atomicAdd(&deg_in[d.y], 1);
    atomicAdd(&deg_in[d.z], 1);  atomicAdd(&deg_in[d.w], 1);
}

// two exclusive scans (one block each): block 0: degA->offA, block 1: degB->offB
__global__ __launch_bounds__(1024) void scan_kernel(const int* __restrict__ degA, int* __restrict__ offA,
                                                    const int* __restrict__ degB, int* __restrict__ offB) {
    const int* deg = blockIdx.x ? degB : degA;
    int* off = blockIdx.x ? offB : offA;
    __shared__ int wsum[16];
    __shared__ int s_run;
    const int t = threadIdx.x, lane = t & 63, wid = t >> 6;
    if (t == 0) s_run = 0;
    __syncthreads();
    for (int base = 0; base < N_NODES; base += 1024) {
        int i = base + t;
        int v = (i < N_NODES) ? deg[i] : 0;
        int xv = v;
        #pragma unroll
        for (int d = 1; d < 64; d <<= 1) {
            int tt = __shfl_up(xv, d, 64);
            if (lane >= d) xv += tt;
        }
        if (lane == 63) wsum[wid] = xv;
        __syncthreads();
        int add = s_run;
        for (int w = 0; w < wid; ++w) add += wsum[w];
        if (i < N_NODES) off[i] = add + xv - v;   // exclusive
        __syncthreads();
        if (t == 1023) s_run = add + xv;
        __syncthreads();
    }
    if (t == 0) off[N_NODES] = s_run;
}

__global__ void fill_csr_kernel(const int* __restrict__ ei,
                                const int* __restrict__ deg_out, const int* __restrict__ deg_in,
                                const int* __restrict__ off_dst, const int* __restrict__ off_src,
                                int* __restrict__ cur_dst, int* __restrict__ cur_src,
                                int2* __restrict__ csrd, int2* __restrict__ csrs) {
    int e = blockIdx.x * blockDim.x + threadIdx.x;
    if (e >= N_EDGES) return;
    int s = ei[e], d = ei[N_EDGES + e];
    // exact IEEE 1/deg computed once here; stored f32 (matches reference numerics)
    int p = off_dst[d] + atomicAdd(&cur_dst[d], 1);
    csrd[p] = make_int2(s, __float_as_int(1.0f / (float)deg_out[s]));  // w = 1/deg_out[src]
    int q = off_src[s] + atomicAdd(&cur_src[s], 1);
    csrs[q] = make_int2(d, __float_as_int(1.0f / (float)deg_in[d]));   // w = 1/deg_in[dst]
}

// gather v3: 16-lane node group, 16 edges/iter. Lane l loads csr[e0+l] (one 8B load),
// then 4 rounds of shfl-broadcast: round r covers edges e0+4r+u (u=l>>2), each lane
// gathers its fq float4 chunk. VMEM ops: 5/edge (1 csr + 4 row) vs 8 before.
// Per-lane accumulation order identical to R4's gather4d (edges u,4+u,8+u,12+u,...).
__device__ __forceinline__ float4 gather_v3(const int2* __restrict__ csr, int beg, int end,
                                            int l, int u, int fq, const float* __restrict__ src) {
    float4 acc = {0.f, 0.f, 0.f, 0.f};
    for (int e0 = beg; e0 < end; e0 += 16) {
        int ee = e0 + l;
        int2 p = (ee < end) ? csr[ee] : make_int2(0, 0);   // pad: idx 0, w +0.0f
        int   il = p.x;
        float wl = __int_as_float(p.y);
        #pragma unroll
        for (int r = 0; r < 4; ++r) {
            if (e0 + 4 * r >= end) break;                  // uniform within the group
            int srcl = 4 * r + u;
            float w  = __shfl(wl, srcl, 16);
            int  idx = __shfl(il, srcl, 16);
            const float4 rw = *(const float4*)&src[idx * FEAT + fq * 4];
            acc.x += w * rw.x; acc.y += w * rw.y;
            acc.z += w * rw.z; acc.w += w * rw.w;
        }
    }
    return acc;
}

__device__ __forceinline__ float4 reduce_u(float4 a) {
    a.x += __shfl_xor(a.x, 4); a.y += __shfl_xor(a.y, 4);
    a.z += __shfl_xor(a.z, 4); a.w += __shfl_xor(a.w, 4);
    a.x += __shfl_xor(a.x, 8); a.y += __shfl_xor(a.y, 8);
    a.z += __shfl_xor(a.z, 8); a.w += __shfl_xor(a.w, 8);
    return a;
}

// k=0,1: slab slots (f32): 0 = x, 1 = T1o, 4 = x, 5 = T1i
__global__ __launch_bounds__(256) void init_kernel(
    const float* __restrict__ x,
    const int* __restrict__ off_dst, const int2* __restrict__ csrd,
    const int* __restrict__ off_src, const int2* __restrict__ csrs,
    float* __restrict__ slab) {
    const int t = threadIdx.x;
    const int g = t >> 4, l = t & 15, u = l >> 2, fq = l & 3;
    const int i = blockIdx.x * 16 + g;
    const int bD = off_dst[i], eD = off_dst[i + 1];
    const int bS = off_src[i], eS = off_src[i + 1];
    float4 aO = reduce_u(gather_v3(csrd, bD, eD, l, u, fq, x));
    float4 aI = reduce_u(gather_v3(csrs, bS, eS, l, u, fq, x));
    if (u == 0) {
        const int ro = i * FEAT + fq * 4;
        float4 xr = *(const float4*)&x[ro];
        *(float4*)&slab[0 * SLOT + ro] = xr;   // T0 (dir O)
        *(float4*)&slab[4 * SLOT + ro] = xr;   // T0 (dir I)
        *(float4*)&slab[1 * SLOT + ro] = aO;   // T1o
        *(float4*)&slab[5 * SLOT + ro] = aI;   // T1i
    }
}

// Chebyshev step k: T_k = 2*P*T_{k-1} - T_{k-2} (both dirs); slab slots serve as ping-pong.
__global__ __launch_bounds__(256) void step_kernel(
    const int* __restrict__ off_dst, const int2* __restrict__ csrd,
    const int* __restrict__ off_src, const int2* __restrict__ csrs,
    const float* __restrict__ prevO, const float* __restrict__ ppO, float* __restrict__ outO,
    const float* __restrict__ prevI, const float* __restrict__ ppI, float* __restrict__ outI) {
    const int t = threadIdx.x;
    const int g = t >> 4, l = t & 15, u = l >> 2, fq = l & 3;
    const int i = blockIdx.x * 16 + g;
    const int bD = off_dst[i], eD = off_dst[i + 1];
    const int bS = off_src[i], eS = off_src[i + 1];
    float4 aO = reduce_u(gather_v3(csrd, bD, eD, l, u, fq, prevO));
    float4 aI = reduce_u(gather_v3(csrs, bS, eS, l, u, fq, prevI));
    if (u == 0) {
        const int ro = i * FEAT + fq * 4;
        float4 pO = *(const float4*)&ppO[ro];
        float4 pI = *(const float4*)&ppI[ro];
        float4 t2o, t2i;
        t2o.x = 2.f * aO.x - pO.x; t2o.y = 2.f * aO.y - pO.y;
        t2o.z = 2.f * aO.z - pO.z; t2o.w = 2.f * aO.w - pO.w;
        t2i.x = 2.f * aI.x - pI.x; t2i.y = 2.f * aI.y - pI.y;
        t2i.z = 2.f * aI.z - pI.z; t2i.w = 2.f * aI.w - pI.w;
        *(float4*)&outO[ro] = t2o;
        *(float4*)&outI[ro] = t2i;
    }
}

// Wcat[s][f][c] f32: s=d*32+k; c<64 -> Wz, c>=64 -> Wh (rows f<16 only)
__global__ void wcat_kernel(const float* __restrict__ Wz, const float* __restrict__ Wh,
                            float* __restrict__ wcat) {
    int idx = blockIdx.x * blockDim.x + threadIdx.x;   // 64*16*128
    if (idx >= 64 * 16 * 128) return;
    int s = idx >> 11, f = (idx >> 7) & 15, c = idx & 127;
    float v = (c < 64) ? Wz[s * WSL + f * 64 + c] : Wh[s * WSL + f * 64 + (c - 64)];
    wcat[idx] = v;
}

// batched GEMM over one 4-k batch: Hz|Hh[node,c] (+)= sum over 8 slots (si<4 dir0, si>=4 dir1)
// of slab[si][node][f] * wcat[(si>>2)*32 + b4 + (si&3)][f][c].  M-tile 128, N=128, 8x8/thread.
__global__ __launch_bounds__(256) void gemm_kernel(
    const float* __restrict__ slab, const float* __restrict__ wcat,
    const float* __restrict__ bz, const float* __restrict__ bh,
    float* __restrict__ Hz, float* __restrict__ Hh, int b4, int first) {
    __shared__ float As[128][20];    // stride 20 keeps float4 stores 16B-aligned
    __shared__ float Ws[16][132];
    const int t = threadIdx.x;
    const int tx = t & 15, ty = t >> 4;
    const int node0 = blockIdx.x * 128;
    float acc[8][8];
    #pragma unroll
    for (int j = 0; j < 8; ++j)
        #pragma unroll
        for (int i = 0; i < 8; ++i) acc[j][i] = 0.f;

    for (int si = 0; si < 8; ++si) {
        // load A: 128 nodes x 16 f32 (512 float4s, 2 per thread)
        #pragma unroll
        for (int it = 0; it < 2; ++it) {
            int id = t + 256 * it;
            int r = id >> 2, q = id & 3;
            int node = node0 + r;
            float4 v = make_float4(0.f, 0.f, 0.f, 0.f);
            if (node < N_NODES) v = *(const float4*)&slab[(size_t)si * SLOT + node * FEAT + q * 4];
            *(float4*)&As[r][q * 4] = v;
        }
        // load W slice: 16 x 128 f32
        {
            int sg = (si >> 2) * 32 + b4 + (si & 3);
            const float* wsrc = wcat + (size_t)sg * 2048;
            int idx = t * 8;
            int kk = idx >> 7, c = idx & 127;
            *(float4*)&Ws[kk][c]     = *(const float4*)&wsrc[kk * 128 + c];
            *(float4*)&Ws[kk][c + 4] = *(const float4*)&wsrc[kk * 128 + c + 4];
        }
        __syncthreads();
        #pragma unroll
        for (int kk = 0; kk < 16; ++kk) {
            float a[8], w[8];
            #pragma unroll
            for (int j = 0; j < 8; ++j) a[j] = As[ty + 16 * j][kk];
            #pragma unroll
            for (int i = 0; i < 8; ++i) w[i] = Ws[kk][tx + 16 * i];
            #pragma unroll
            for (int j = 0; j < 8; ++j)
                #pragma unroll
                for (int i = 0; i < 8; ++i) acc[j][i] += a[j] * w[i];
        }
        __syncthreads();
    }
    // epilogue: cols 0..63 -> Hz, 64..127 -> Hh
    #pragma unroll
    for (int j = 0; j < 8; ++j) {
        int node = node0 + ty + 16 * j;
        if (node >= N_NODES) continue;
        #pragma unroll
        for (int i = 0; i < 4; ++i) {
            int c = tx + 16 * i;
            float* p = &Hz[(size_t)node * 64 + c];
            *p = first ? (bz[c] + acc[j][i]) : (*p + acc[j][i]);
        }
        #pragma unroll
        for (int i = 4; i < 8; ++i) {
            int c = tx + 16 * (i - 4);
            float* p = &Hh[(size_t)node * 64 + c];
            *p = first ? (bh[c] + acc[j][i]) : (*p + acc[j][i]);
        }
    }
}

// H = (1-sigmoid(Hz))*tanh(Hh); out = relu(H) @ lin_w + lin_b
__global__ __launch_bounds__(256) void final_kernel(
    const float* __restrict__ Hz, const float* __restrict__ Hh,
    const float* __restrict__ lin_w, const float* __restrict__ lin_b,
    float* __restrict__ out) {
    __shared__ float s_h[32][65];
    const int t = threadIdx.x;
    const int base = blockIdx.x * 32;
    #pragma unroll
    for (int r = 0; r < 8; ++r) {
        int idx = r * 256 + t;
        int n = idx >> 6, h = idx & 63;
        int i = base + n;
        float v = 0.f;
        if (i < N_NODES) {
            float z = 1.f / (1.f + __expf(-Hz[i * 64 + h]));
            float ht = tanhf(Hh[i * 64 + h]);
            v = fmaxf(0.f, (1.f - z) * ht);
        }
        s_h[n][h] = v;
    }
    __syncthreads();
    int n = t >> 3, c = t & 7;
    int i = base + n;
    if (i < N_NODES) {
        float acc = lin_b[c];
        #pragma unroll
        for (int h = 0; h < 64; ++h) acc += s_h[n][h] * lin_w[h * 8 + c];
        out[i * NCLS + c] = acc;
    }
}

extern "C" void kernel_launch(void* const* d_in, const int* in_sizes, int n_in,
                              void* d_out, int out_size, void* d_ws, size_t ws_size,
                              hipStream_t stream) {
    const float* x   = (const float*)d_in[0];
    const int*   ei  = (const int*)d_in[1];
    const float* Wz  = (const float*)d_in[2];
    const float* bz  = (const float*)d_in[3];
    // d_in[4] = W_r, d_in[5] = b_r : unused (H0 == 0 makes R irrelevant)
    const float* Wh  = (const float*)d_in[6];
    const float* bh  = (const float*)d_in[7];
    const float* lw  = (const float*)d_in[8];
    const float* lb  = (const float*)d_in[9];
    float* out = (float*)d_out;
    char* ws = (char*)d_ws;

    int*  deg_out = (int*)(ws + OFF_DEG_OUT);
    int*  deg_in  = (int*)(ws + OFF_DEG_IN);
    int*  cur_dst = (int*)(ws + OFF_CUR_DST);
    int*  cur_src = (int*)(ws + OFF_CUR_SRC);
    int*  off_dst = (int*)(ws + OFF_OFF_DST);
    int*  off_src = (int*)(ws + OFF_OFF_SRC);
    int2* csrd    = (int2*)(ws + OFF_CSRD);
    int2* csrs    = (int2*)(ws + OFF_CSRS);
    float* Hz   = (float*)(ws + OFF_HZ);
    float* Hh   = (float*)(ws + OFF_HH);
    float* slab = (float*)(ws + OFF_SLAB);
    float* wcat = (float*)(ws + OFF_WCAT);

    hipMemsetAsync(ws, 0, ZERO_BYTES, stream);

    const int EB = (N_EDGES + 255) / 256;       // 3125
    const int NB16 = N_NODES / 16;              // 3125 (exact)
    count_deg_kernel<<<(N_EDGES / 4 + 255) / 256, 256, 0, stream>>>(ei, deg_out, deg_in);
    scan_kernel<<<2, 1024, 0, stream>>>(deg_in, off_dst, deg_out, off_src);
    fill_csr_kernel<<<EB, 256, 0, stream>>>(ei, deg_out, deg_in, off_dst, off_src,
                                            cur_dst, cur_src, csrd, csrs);
    wcat_kernel<<<(64 * 16 * 128 + 255) / 256, 256, 0, stream>>>(Wz, Wh, wcat);
    init_kernel<<<NB16, 256, 0, stream>>>(x, off_dst, csrd, off_src, csrs, slab);

    for (int k = 2; k < KORD; ++k) {
        const float* prevO = slab + (size_t)(((k - 1) & 3)) * SLOT;
        const float* ppO   = slab + (size_t)(((k - 2) & 3)) * SLOT;
        float*       outO  = slab + (size_t)((k & 3)) * SLOT;
        const float* prevI = slab + (size_t)(4 + ((k - 1) & 3)) * SLOT;
        const float* ppI   = slab + (size_t)(4 + ((k - 2) & 3)) * SLOT;
        float*       outI  = slab + (size_t)(4 + (k & 3)) * SLOT;
        step_kernel<<<NB16, 256, 0, stream>>>(off_dst, csrd, off_src, csrs,
                                              prevO, ppO, outO, prevI, ppI, outI);
        if ((k & 3) == 3) {   // batch of 4 complete: slots 0..3 = T_{k-3..k} (O), 4..7 (I)
            gemm_kernel<<<(N_NODES + 127) / 128, 256, 0, stream>>>(
                slab, wcat, bz, bh, Hz, Hh, k - 3, (k == 3) ? 1 : 0);
        }
    }
    final_kernel<<<(N_NODES + 31) / 32, 256, 0, stream>>>(Hz, Hh, lw, lb, out);
}

// Round 7
// 849.541 us; speedup vs baseline: 1.4523x; 1.4523x over previous
//
#include <hip/hip_runtime.h>
#include <math.h>

#define N_NODES 50000
#define N_EDGES 800000
#define FEAT    16
#define HID     64
#define KORD    32
#define NCLS    8

// W[d,k,f,c] flat index = (d*KORD + k)*80*64 + f*64 + c ; only rows f<16 matter (H0==0).
#define WSL     5120   // 80*64, per-(d,k) slice stride in floats
#define SLOT    (N_NODES * FEAT)   // 800000 elements per slab slot

typedef __attribute__((ext_vector_type(8))) short bf8_t;   // 8 bf16 (4 VGPRs)
typedef __attribute__((ext_vector_type(4))) float f32x4;

static constexpr size_t Aln(size_t x) { return (x + 255) & ~size_t(255); }

// ---- workspace layout (bytes), total ~213 MB ----
static constexpr size_t OFF_DEG_OUT = 0;
static constexpr size_t OFF_DEG_IN  = OFF_DEG_OUT + Aln(N_NODES * 4);
static constexpr size_t OFF_CUR_DST = OFF_DEG_IN  + Aln(N_NODES * 4);
static constexpr size_t OFF_CUR_SRC = OFF_CUR_DST + Aln(N_NODES * 4);
static constexpr size_t ZERO_BYTES  = OFF_CUR_SRC + Aln(N_NODES * 4);   // zero [0, ZERO_BYTES)
static constexpr size_t OFF_OFF_DST = ZERO_BYTES;
static constexpr size_t OFF_OFF_SRC = OFF_OFF_DST + Aln((N_NODES + 1) * 4);
static constexpr size_t OFF_CSRD    = OFF_OFF_SRC + Aln((N_NODES + 1) * 4);  // uint{deg:16|idx:16}
static constexpr size_t OFF_CSRS    = OFF_CSRD + Aln(N_EDGES * 4);
static constexpr size_t OFF_SLAB    = OFF_CSRS + Aln(N_EDGES * 4);           // 64 f32 slots (dir*32+k)
static constexpr size_t OFF_BSZH    = OFF_SLAB + Aln((size_t)64 * SLOT * 4);
static constexpr size_t OFF_BSZL    = OFF_BSZH + Aln((size_t)32 * 8 * 64 * 8 * 2);
static constexpr size_t WS_TOTAL    = OFF_BSZL + Aln((size_t)32 * 8 * 64 * 8 * 2);

__device__ __forceinline__ ushort f2bf(float v) {   // f32 -> bf16 (RNE)
    unsigned int b = __float_as_uint(v);
    b += 0x7FFFu + ((b >> 16) & 1u);
    return (ushort)(b >> 16);
}
__device__ __forceinline__ float bf2f(ushort h) {
    return __uint_as_float((unsigned int)h << 16);
}

__global__ void count_deg_kernel(const int* __restrict__ ei,
                                 int* __restrict__ deg_out, int* __restrict__ deg_in) {
    int e4 = blockIdx.x * blockDim.x + threadIdx.x;   // 4 edges per thread
    if (e4 * 4 >= N_EDGES) return;
    int4 s = *(const int4*)&ei[e4 * 4];
    int4 d = *(const int4*)&ei[N_EDGES + e4 * 4];
    atomicAdd(&deg_out[s.x], 1); atomicAdd(&deg_out[s.y], 1);
    atomicAdd(&deg_out[s.z], 1); atomicAdd(&deg_out[s.w], 1);
    atomicAdd(&deg_in[d.x], 1);  atomicAdd(&deg_in[d.y], 1);
    atomicAdd(&deg_in[d.z], 1);  atomicAdd(&deg_in[d.w], 1);
}

// two exclusive scans (one block each): block 0: degA->offA, block 1: degB->offB
__global__ __launch_bounds__(1024) void scan_kernel(const int* __restrict__ degA, int* __restrict__ offA,
                                                    const int* __restrict__ degB, int* __restrict__ offB) {
    const int* deg = blockIdx.x ? degB : degA;
    int* off = blockIdx.x ? offB : offA;
    __shared__ int wsum[16];
    __shared__ int s_run;
    const int t = threadIdx.x, lane = t & 63, wid = t >> 6;
    if (t == 0) s_run = 0;
    __syncthreads();
    for (int base = 0; base < N_NODES; base += 1024) {
        int i = base + t;
        int v = (i < N_NODES) ? deg[i] : 0;
        int xv = v;
        #pragma unroll
        for (int d = 1; d < 64; d <<= 1) {
            int tt = __shfl_up(xv, d, 64);
            if (lane >= d) xv += tt;
        }
        if (lane == 63) wsum[wid] = xv;
        __syncthreads();
        int add = s_run;
        for (int w = 0; w < wid; ++w) add += wsum[w];
        if (i < N_NODES) off[i] = add + xv - v;   // exclusive
        __syncthreads();
        if (t == 1023) s_run = add + xv;
        __syncthreads();
    }
    if (t == 0) off[N_NODES] = s_run;
}

__global__ void fill_csr_kernel(const int* __restrict__ ei,
                                const int* __restrict__ deg_out, const int* __restrict__ deg_in,
                                const int* __restrict__ off_dst, const int* __restrict__ off_src,
                                int* __restrict__ cur_dst, int* __restrict__ cur_src,
                                unsigned int* __restrict__ csrd, unsigned int* __restrict__ csrs) {
    int e = blockIdx.x * blockDim.x + threadIdx.x;
    if (e >= N_EDGES) return;
    int s = ei[e], d = ei[N_EDGES + e];
    // packed entry: {deg:16 | idx:16}; weight computed in-gather as exact 1.0f/deg
    int p = off_dst[d] + atomicAdd(&cur_dst[d], 1);
    csrd[p] = ((unsigned int)deg_out[s] << 16) | (unsigned int)s;  // w = 1/deg_out[src]
    int q = off_src[s] + atomicAdd(&cur_src[s], 1);
    csrs[q] = ((unsigned int)deg_in[d] << 16) | (unsigned int)d;   // w = 1/deg_in[dst]
}

// gather (R4-proven): 16-lane node group, lane = (u=edge 0..3, fq=chunk 0..3), 16 edges/iter.
__device__ __forceinline__ float4 gather4d(const unsigned int* __restrict__ csr, int beg, int end,
                                           int u, int fq, const float* __restrict__ src) {
    float4 acc = {0.f, 0.f, 0.f, 0.f};
    for (int e0 = beg; e0 < end; e0 += 16) {
        int ea = e0 + u, eb = e0 + 4 + u, ec = e0 + 8 + u, ed = e0 + 12 + u;
        unsigned int pa = (ea < end) ? csr[ea] : 0x10000u;   // pad: deg=1, idx=0
        unsigned int pb = (eb < end) ? csr[eb] : 0x10000u;
        unsigned int pc = (ec < end) ? csr[ec] : 0x10000u;
        unsigned int pd = (ed < end) ? csr[ed] : 0x10000u;
        float wa = (ea < end) ? 1.0f / (float)(pa >> 16) : 0.0f;  // exact IEEE div, matches ref
        float wb = (eb < end) ? 1.0f / (float)(pb >> 16) : 0.0f;
        float wc = (ec < end) ? 1.0f / (float)(pc >> 16) : 0.0f;
        float wd = (ed < end) ? 1.0f / (float)(pd >> 16) : 0.0f;
        const float4 ra = *(const float4*)&src[(pa & 0xFFFFu) * FEAT + fq * 4];
        const float4 rb = *(const float4*)&src[(pb & 0xFFFFu) * FEAT + fq * 4];
        const float4 rc = *(const float4*)&src[(pc & 0xFFFFu) * FEAT + fq * 4];
        const float4 rd = *(const float4*)&src[(pd & 0xFFFFu) * FEAT + fq * 4];
        acc.x += wa * ra.x + wb * rb.x + wc * rc.x + wd * rd.x;
        acc.y += wa * ra.y + wb * rb.y + wc * rc.y + wd * rd.y;
        acc.z += wa * ra.z + wb * rb.z + wc * rc.z + wd * rd.z;
        acc.w += wa * ra.w + wb * rb.w + wc * rc.w + wd * rd.w;
    }
    return acc;
}

__device__ __forceinline__ float4 reduce_u(float4 a) {
    a.x += __shfl_xor(a.x, 4); a.y += __shfl_xor(a.y, 4);
    a.z += __shfl_xor(a.z, 4); a.w += __shfl_xor(a.w, 4);
    a.x += __shfl_xor(a.x, 8); a.y += __shfl_xor(a.y, 8);
    a.z += __shfl_xor(a.z, 8); a.w += __shfl_xor(a.w, 8);
    return a;
}

// k=0,1 (one direction per blockIdx.y): slab[dir*32+0] = x, slab[dir*32+1] = T1 (all f32)
__global__ __launch_bounds__(256) void init_kernel(
    const float* __restrict__ x,
    const int* __restrict__ off_dst, const unsigned int* __restrict__ csrd,
    const int* __restrict__ off_src, const unsigned int* __restrict__ csrs,
    float* __restrict__ slab) {
    const int dir = blockIdx.y;
    const int* off = dir ? off_src : off_dst;
    const unsigned int* csr = dir ? csrs : csrd;
    const int t = threadIdx.x;
    const int g = t >> 4, l = t & 15, u = l >> 2, fq = l & 3;
    const int i = blockIdx.x * 16 + g;
    const int b = off[i], e = off[i + 1];
    float4 a = reduce_u(gather4d(csr, b, e, u, fq, x));
    if (u == 0) {
        const int ro = i * FEAT + fq * 4;
        float4 xr = *(const float4*)&x[ro];
        *(float4*)&slab[(size_t)(dir * 32 + 0) * SLOT + ro] = xr;
        *(float4*)&slab[(size_t)(dir * 32 + 1) * SLOT + ro] = a;
    }
}

// Chebyshev step k (one direction per blockIdx.y): slab[dir*32+k] = 2*P*slab[k-1] - slab[k-2]
__global__ __launch_bounds__(256) void step_kernel(
    const int* __restrict__ off_dst, const unsigned int* __restrict__ csrd,
    const int* __restrict__ off_src, const unsigned int* __restrict__ csrs,
    float* __restrict__ slab, int k) {
    const int dir = blockIdx.y;
    const int* off = dir ? off_src : off_dst;
    const unsigned int* csr = dir ? csrs : csrd;
    const float* prev = slab + (size_t)(dir * 32 + k - 1) * SLOT;
    const float* pp   = slab + (size_t)(dir * 32 + k - 2) * SLOT;
    float*       outp = slab + (size_t)(dir * 32 + k) * SLOT;
    const int t = threadIdx.x;
    const int g = t >> 4, l = t & 15, u = l >> 2, fq = l & 3;
    const int i = blockIdx.x * 16 + g;
    const int b = off[i], e = off[i + 1];
    float4 a = reduce_u(gather4d(csr, b, e, u, fq, prev));
    if (u == 0) {
        const int ro = i * FEAT + fq * 4;
        float4 p = *(const float4*)&pp[ro];
        float4 t2;
        t2.x = 2.f * a.x - p.x; t2.y = 2.f * a.y - p.y;
        t2.z = 2.f * a.z - p.z; t2.w = 2.f * a.w - p.w;
        *(float4*)&outp[ro] = t2;
    }
}

// Build MFMA-swizzled bf16 hi/lo weight fragments.
// Fragment element (kc, nc, lane l, i): si = kc*2 + ((l>>4)>>1); f = ((l>>4)&1)*8 + i;
// c = nc*16 + (l&15); value = W[d=si>>5][kz=si&31][f][c] (c<64 -> Wz, else Wh col c-64).
__global__ void wswiz_kernel(const float* __restrict__ Wz, const float* __restrict__ Wh,
                             ushort* __restrict__ bszh, ushort* __restrict__ bszl) {
    int idx = blockIdx.x * blockDim.x + threadIdx.x;   // 32*8*64 = 16384 threads
    if (idx >= 32 * 8 * 64) return;
    int l  = idx & 63;
    int nc = (idx >> 6) & 7;
    int kc = idx >> 9;
    int si = kc * 2 + ((l >> 4) >> 1);
    int f0 = ((l >> 4) & 1) * 8;
    int c  = nc * 16 + (l & 15);
    const float* W = (c < 64) ? Wz : Wh;
    int cc = (c < 64) ? c : c - 64;
    ushort vh[8], vl[8];
    #pragma unroll
    for (int i = 0; i < 8; ++i) {
        float v = W[(size_t)si * WSL + (f0 + i) * 64 + cc];
        ushort h = f2bf(v);
        vh[i] = h;
        vl[i] = f2bf(v - bf2f(h));
    }
    ushort* dh = &bszh[(size_t)idx * 8];
    *(ushort4*)dh       = make_ushort4(vh[0], vh[1], vh[2], vh[3]);
    *(ushort4*)(dh + 4) = make_ushort4(vh[4], vh[5], vh[6], vh[7]);
    ushort* dl = &bszl[(size_t)idx * 8];
    *(ushort4*)dl       = make_ushort4(vl[0], vl[1], vl[2], vl[3]);
    *(ushort4*)(dl + 4) = make_ushort4(vl[4], vl[5], vl[6], vl[7]);
}

// Fused readout: H = bias + sum_{si} T_si @ W_si via split-bf16 MFMA (HiHi + HiLo + LoHi),
// then H := (1-sigmoid(Hz))*tanh(Hh), out = relu(H) @ lin_w + lin_b.
// Block = 4 waves x 16 nodes = 64 nodes. Wave: acc[8] 16x16 tiles (cols 0..127).
__global__ __launch_bounds__(256) void final_kernel(
    const float* __restrict__ slab, const ushort* __restrict__ bszh, const ushort* __restrict__ bszl,
    const float* __restrict__ bz, const float* __restrict__ bh,
    const float* __restrict__ lin_w, const float* __restrict__ lin_b,
    float* __restrict__ out) {
    const int t = threadIdx.x;
    const int w = t >> 6, l = t & 63;
    const int cl = l & 15, hi = l >> 4;
    const int n0 = blockIdx.x * 64 + w * 16;

    f32x4 acc[8];
    #pragma unroll
    for (int nc = 0; nc < 8; ++nc) {
        int c = nc * 16 + cl;
        float bias = (c < 64) ? bz[c] : bh[c - 64];
        acc[nc] = (f32x4){bias, bias, bias, bias};
    }

    const int nodeA = n0 + cl;                 // A-fragment row (node)
    const int aOk = (nodeA < N_NODES);
    const int siAdd = (hi >> 1);               // 0 or 1
    const int f0 = (hi & 1) * 8;

    for (int kc = 0; kc < 32; ++kc) {
        bf8_t aHi = (bf8_t)0, aLo = (bf8_t)0;
        if (aOk) {
            int si = kc * 2 + siAdd;
            const float* ap = &slab[(size_t)si * SLOT + nodeA * FEAT + f0];
            float4 a0 = *(const float4*)ap;
            float4 a1 = *(const float4*)(ap + 4);
            float av[8] = {a0.x, a0.y, a0.z, a0.w, a1.x, a1.y, a1.z, a1.w};
            #pragma unroll
            for (int i = 0; i < 8; ++i) {
                ushort h = f2bf(av[i]);
                aHi[i] = (short)h;
                aLo[i] = (short)f2bf(av[i] - bf2f(h));
            }
        }
        #pragma unroll
        for (int nc = 0; nc < 8; ++nc) {
            const size_t fo = (size_t)(((kc * 8 + nc) * 64) + l) * 8;
            bf8_t bHi = *(const bf8_t*)&bszh[fo];
            bf8_t bLo = *(const bf8_t*)&bszl[fo];
            acc[nc] = __builtin_amdgcn_mfma_f32_16x16x32_bf16(aHi, bHi, acc[nc], 0, 0, 0);
            acc[nc] = __builtin_amdgcn_mfma_f32_16x16x32_bf16(aLo, bHi, acc[nc], 0, 0, 0);
            acc[nc] = __builtin_amdgcn_mfma_f32_16x16x32_bf16(aHi, bLo, acc[nc], 0, 0, 0);
        }
    }

    // epilogue: acc[nc][i] = H at node n0 + hi*4 + i, col nc*16+cl (nc<4: Hz, nc>=4: Hh)
    float po[4][8];
    #pragma unroll
    for (int i = 0; i < 4; ++i)
        #pragma unroll
        for (int cls = 0; cls < 8; ++cls) po[i][cls] = 0.f;
    #pragma unroll
    for (int i = 0; i < 4; ++i) {
        #pragma unroll
        for (int nc = 0; nc < 4; ++nc) {
            float hz = acc[nc][i], hh = acc[nc + 4][i];
            float z  = 1.f / (1.f + __expf(-hz));
            float ht = tanhf(hh);
            float v  = fmaxf(0.f, (1.f - z) * ht);
            const float* lwr = &lin_w[(nc * 16 + cl) * 8];
            #pragma unroll
            for (int cls = 0; cls < 8; ++cls) po[i][cls] += v * lwr[cls];
        }
    }
    #pragma unroll
    for (int m = 1; m < 16; m <<= 1) {
        #pragma unroll
        for (int i = 0; i < 4; ++i)
            #pragma unroll
            for (int cls = 0; cls < 8; ++cls)
                po[i][cls] += __shfl_xor(po[i][cls], m, 16);
    }
    if (cl < 8) {
        #pragma unroll
        for (int i = 0; i < 4; ++i) {
            int node = n0 + hi * 4 + i;
            if (node < N_NODES) out[node * NCLS + cl] = po[i][cl] + lin_b[cl];
        }
    }
}

extern "C" void kernel_launch(void* const* d_in, const int* in_sizes, int n_in,
                              void* d_out, int out_size, void* d_ws, size_t ws_size,
                              hipStream_t stream) {
    const float* x   = (const float*)d_in[0];
    const int*   ei  = (const int*)d_in[1];
    const float* Wz  = (const float*)d_in[2];
    const float* bz  = (const float*)d_in[3];
    // d_in[4] = W_r, d_in[5] = b_r : unused (H0 == 0 makes R irrelevant)
    const float* Wh  = (const float*)d_in[6];
    const float* bh  = (const float*)d_in[7];
    const float* lw  = (const float*)d_in[8];
    const float* lb  = (const float*)d_in[9];
    float* out = (float*)d_out;
    char* ws = (char*)d_ws;

    int*  deg_out = (int*)(ws + OFF_DEG_OUT);
    int*  deg_in  = (int*)(ws + OFF_DEG_IN);
    int*  cur_dst = (int*)(ws + OFF_CUR_DST);
    int*  cur_src = (int*)(ws + OFF_CUR_SRC);
    int*  off_dst = (int*)(ws + OFF_OFF_DST);
    int*  off_src = (int*)(ws + OFF_OFF_SRC);
    unsigned int* csrd = (unsigned int*)(ws + OFF_CSRD);
    unsigned int* csrs = (unsigned int*)(ws + OFF_CSRS);
    float*  slab = (float*)(ws + OFF_SLAB);
    ushort* bszh = (ushort*)(ws + OFF_BSZH);
    ushort* bszl = (ushort*)(ws + OFF_BSZL);

    hipMemsetAsync(ws, 0, ZERO_BYTES, stream);

    const int EB = (N_EDGES + 255) / 256;       // 3125
    const int NB16 = N_NODES / 16;              // 3125 (exact)
    count_deg_kernel<<<(N_EDGES / 4 + 255) / 256, 256, 0, stream>>>(ei, deg_out, deg_in);
    scan_kernel<<<2, 1024, 0, stream>>>(deg_in, off_dst, deg_out, off_src);
    fill_csr_kernel<<<EB, 256, 0, stream>>>(ei, deg_out, deg_in, off_dst, off_src,
                                            cur_dst, cur_src, csrd, csrs);
    wswiz_kernel<<<(32 * 8 * 64 + 255) / 256, 256, 0, stream>>>(Wz, Wh, bszh, bszl);
    init_kernel<<<dim3(NB16, 2), 256, 0, stream>>>(x, off_dst, csrd, off_src, csrs, slab);

    for (int k = 2; k < KORD; ++k)
        step_kernel<<<dim3(NB16, 2), 256, 0, stream>>>(off_dst, csrd, off_src, csrs, slab, k);

    final_kernel<<<(N_NODES + 63) / 64, 256, 0, stream>>>(slab, bszh, bszl, bz, bh, lw, lb, out);
}